// Round 3
// baseline (197.431 us; speedup 1.0000x reference)
//
#include <hip/hip_runtime.h>

// ---------------------------------------------------------------------------
// Attention block: y = (softmax(scale*(xWq)(xWk)^T) (xWv)) Wout^T
// b=4 n=2048 c=512 h=8 d=64.  bf16 MFMA, fp32 accumulate.
//
// R2:
//   - GEMMs rebuilt on the m97 recipe: 128-wide tiles, BK=64,
//     global_load_lds width=16, XOR chunk swizzle (c ^ (row&7)) so the
//     unpadded DMA-contiguous LDS layout still has ~2-way-conflict b128 reads
//   - attn: Ps writes packed to b32 via __shfl_xor pair-packing (VALU pipe)
//     -> 64 ds_write_b16 becomes 32 ds_write_b32 per block-tile
//
// Fragment layouts (HW-verified, guide §3):
//   16x16x32: A[m=lane&15][k=(lane>>4)*8+j], C/D: col=lane&15, row=(lane>>4)*4+reg
//   32x32x16: A[m=lane&31][k=(lane>>5)*8+j], C/D: col=lane&31,
//             row=(reg&3)+8*(reg>>2)+4*(lane>>5)
// ---------------------------------------------------------------------------

typedef unsigned short u16;
typedef __attribute__((ext_vector_type(8))) short s16x8;
typedef __attribute__((ext_vector_type(4))) float f32x4;
typedef __attribute__((ext_vector_type(16))) float f32x16;

__device__ __forceinline__ u16 f2bf(float f) {
  unsigned int u = __float_as_uint(f);
  u = (u + 0x7fffu + ((u >> 16) & 1u)) >> 16;   // RNE
  return (u16)u;
}

// async global->LDS, 16 B per lane; lds_base must be wave-uniform
__device__ __forceinline__ void gload16(const u16* g, u16* lds_base) {
  __builtin_amdgcn_global_load_lds(
      (const __attribute__((address_space(1))) unsigned int*)g,
      (__attribute__((address_space(3))) unsigned int*)lds_base, 16, 0, 0);
}

// ---- fp32 -> bf16 bulk convert (4 elems/thread) ---------------------------
__global__ __launch_bounds__(256) void cvt4(const float* __restrict__ in,
                                            u16* __restrict__ out, int n4) {
  int i = blockIdx.x * 256 + threadIdx.x;
  if (i >= n4) return;
  float4 f = ((const float4*)in)[i];
  uint2 o;
  o.x = (unsigned)f2bf(f.x) | ((unsigned)f2bf(f.y) << 16);
  o.y = (unsigned)f2bf(f.z) | ((unsigned)f2bf(f.w) << 16);
  ((uint2*)out)[i] = o;
}

// ---- GEMM  C[M][N] = A[M][512] * B[N][512]^T  (m97-style) -----------------
// 128 x BN tile, BK=64, 4 waves (2x2), per-wave 64 x BN/2 via 16x16x32.
// LDS layout: row-major [rows][64] u16, 16B chunk c of row r stored at
// slot (c ^ (r&7)) -- DMA-contiguous AND ~conflict-free b128 frag reads.
// MODE 0: scatter Q(*scale*log2e)/K -> [bh][n][64], V -> [bh][d][n].
// MODE 1: fp32 store to Cf (ldc=512).
template <int BN, int MODE>
__global__ __launch_bounds__(256) void gemm128(
    const u16* __restrict__ A, const u16* __restrict__ B,
    float* __restrict__ Cf,
    u16* __restrict__ Qp, u16* __restrict__ Kp, u16* __restrict__ Vp) {
  constexpr int K = 512;
  constexpr int JN = BN / 32;           // n-blocks per wave
  __shared__ u16 As[128 * 64];
  __shared__ u16 Bs[BN * 64];
  const int bm0 = blockIdx.x * 128, bn0 = blockIdx.y * BN;
  const int t = threadIdx.x, wave = t >> 6, lane = t & 63;
  const int quad = lane >> 4, l16 = lane & 15;
  const int wm = (wave & 1) * 64, wn = (wave >> 1) * (BN / 2);
  const int lr = lane >> 3, lc = lane & 7;   // staging: 8 rows x 8 chunks
  const int swz = lc ^ lr;                   // (row&7)==lr for 8-row groups

  f32x4 acc[4][JN] = {};

  for (int k0 = 0; k0 < K; k0 += 64) {
    __syncthreads();   // prior iteration's frag reads done
#pragma unroll
    for (int a = 0; a < 4; a++) {
      int r = wave * 32 + a * 8 + lr;
      gload16(A + (size_t)(bm0 + r) * K + k0 + swz * 8,
              &As[(wave * 32 + a * 8) * 64]);
    }
#pragma unroll
    for (int b = 0; b < BN / 32; b++) {
      int r = wave * (BN / 4) + b * 8 + lr;
      gload16(B + (size_t)(bn0 + r) * K + k0 + swz * 8,
              &Bs[(wave * (BN / 4) + b * 8) * 64]);
    }
    __syncthreads();   // drains vmcnt (DMA) + barrier
#pragma unroll
    for (int ks = 0; ks < 2; ks++) {
      s16x8 af[4], bf[JN];
#pragma unroll
      for (int i = 0; i < 4; i++) {
        int m = wm + i * 16 + l16;
        af[i] = *(const s16x8*)(&As[m * 64 + (((ks * 4 + quad) ^ (m & 7)) * 8)]);
      }
#pragma unroll
      for (int j = 0; j < JN; j++) {
        int n = wn + j * 16 + l16;
        bf[j] = *(const s16x8*)(&Bs[n * 64 + (((ks * 4 + quad) ^ (n & 7)) * 8)]);
      }
#pragma unroll
      for (int i = 0; i < 4; i++)
#pragma unroll
        for (int j = 0; j < JN; j++)
          acc[i][j] = __builtin_amdgcn_mfma_f32_16x16x32_bf16(af[i], bf[j], acc[i][j], 0, 0, 0);
    }
  }

#pragma unroll
  for (int i = 0; i < 4; i++)
#pragma unroll
    for (int j = 0; j < JN; j++)
#pragma unroll
      for (int r = 0; r < 4; r++) {
        int m = bm0 + wm + i * 16 + quad * 4 + r;
        int n = bn0 + wn + j * 16 + l16;
        float v = acc[i][j][r];
        if constexpr (MODE == 1) {
          Cf[(size_t)m * 512 + n] = v;
        } else {
          int part = n >> 9;
          int oin = n & 511;
          int head = oin >> 6, dh = oin & 63;
          int bb = m >> 11, tok = m & 2047;
          if (part == 0) {
            size_t idx = ((size_t)(bb * 8 + head) * 2048 + tok) * 64 + dh;
            Qp[idx] = f2bf(v * 0.18033688011112042f);  // scale * log2(e)
          } else if (part == 1) {
            size_t idx = ((size_t)(bb * 8 + head) * 2048 + tok) * 64 + dh;
            Kp[idx] = f2bf(v);
          } else {
            size_t idx = ((size_t)(bb * 8 + head) * 64 + dh) * 2048 + tok;
            Vp[idx] = f2bf(v);   // V transposed: [bh][d][n]
          }
        }
      }
}

// ---- attention: one block = one (b,h) x 64 Q rows, 32x32x16 MFMA ----------
// Q/K: [32][2048][64] bf16; Vt: [32][64][2048] bf16; O: [4][2048][512] bf16.
__global__ __launch_bounds__(256) void attn_kernel(
    const u16* __restrict__ Qg, const u16* __restrict__ Kg,
    const u16* __restrict__ Vtg, u16* __restrict__ Og) {
  __shared__ u16 Qs[64][72];
  __shared__ u16 Ks[64][72];
  __shared__ u16 Vt[64][72];   // Vt[d][j]
  __shared__ u16 Ps[64][72];   // P round-trip C-layout -> A-layout
  __shared__ float Ls[2][64];  // per-wk-half row sums
  const int bh = blockIdx.y;          // 0..31
  const int q0 = blockIdx.x * 64;
  const u16* Qh = Qg + (size_t)bh * 2048 * 64;
  const u16* Kh = Kg + (size_t)bh * 2048 * 64;
  const u16* Vh = Vtg + (size_t)bh * 64 * 2048;
  const int t = threadIdx.x, lane = t & 63, wave = t >> 6;
  const int wq = wave & 1, wk = wave >> 1;   // 2x2 wave grid
  const int l32 = lane & 31, half = lane >> 5;
  const int srow = t >> 2, scolb = (t & 3) * 8;

  // stage Q tile (resident) then hoist A-fragments to registers
#pragma unroll
  for (int p = 0; p < 2; p++) {
    int col = scolb + p * 32;
    *(s16x8*)(&Qs[srow][col]) = *(const s16x8*)(Qh + (size_t)(q0 + srow) * 64 + col);
  }
  __syncthreads();
  s16x8 aq[4];
#pragma unroll
  for (int ks = 0; ks < 4; ks++)
    aq[ks] = *(const s16x8*)(&Qs[wq * 32 + l32][ks * 16 + half * 8]);

  f32x16 o = {};
  float l_part[16];
#pragma unroll
  for (int r = 0; r < 16; r++) l_part[r] = 0.f;

  for (int j0 = 0; j0 < 2048; j0 += 64) {
    __syncthreads();   // prior tile's frag reads done before overwrite
#pragma unroll
    for (int p = 0; p < 2; p++) {
      int col = scolb + p * 32;
      *(s16x8*)(&Ks[srow][col]) = *(const s16x8*)(Kh + (size_t)(j0 + srow) * 64 + col);
      *(s16x8*)(&Vt[srow][col]) = *(const s16x8*)(Vh + (size_t)srow * 2048 + j0 + col);
    }
    __syncthreads();

    // S block: rows wq*32..+31, cols wk*32..+31, contraction over 64
    f32x16 s = {};
#pragma unroll
    for (int ks = 0; ks < 4; ks++) {
      s16x8 bk = *(const s16x8*)(&Ks[wk * 32 + l32][ks * 16 + half * 8]);
      s = __builtin_amdgcn_mfma_f32_32x32x16_bf16(aq[ks], bk, s, 0, 0, 0);
    }

    // p = 2^s (log2e pre-folded); l from truncated-bf16 p;
    // pack col-pairs via shfl_xor (VALU/DPP pipe) -> b32 LDS writes
    unsigned pb[16];
#pragma unroll
    for (int r = 0; r < 16; r++) {
      float p = __builtin_amdgcn_exp2f(s[r]);
      unsigned u = __float_as_uint(p);
      l_part[r] += __uint_as_float(u & 0xffff0000u);
      pb[r] = u >> 16;
    }
    const int odd = l32 & 1;
    const int colb = wk * 32 + (l32 & ~1);
#pragma unroll
    for (int rp = 0; rp < 8; rp++) {
      unsigned v0 = pb[2 * rp], v1 = pb[2 * rp + 1];
      unsigned t0 = __shfl_xor(v0, 1, 64);
      unsigned t1 = __shfl_xor(v1, 1, 64);
      int r = 2 * rp + odd;
      int row = (r & 3) + 8 * (r >> 2) + 4 * half + wq * 32;
      unsigned packed = odd ? (t1 | (v1 << 16)) : (v0 | (t0 << 16));
      *(unsigned*)(&Ps[row][colb]) = packed;
    }
    __syncthreads();   // Ps rows mix wk halves -> cross-wave

    // O block: rows wq*32..+31, d-cols wk*32..+31, contraction over 64 j
#pragma unroll
    for (int ks = 0; ks < 4; ks++) {
      s16x8 ap = *(const s16x8*)(&Ps[wq * 32 + l32][ks * 16 + half * 8]);
      s16x8 bv = *(const s16x8*)(&Vt[wk * 32 + l32][ks * 16 + half * 8]);
      o = __builtin_amdgcn_mfma_f32_32x32x16_bf16(ap, bv, o, 0, 0, 0);
    }
  }

  // row-sum reduce: over 32 cols in-wave, then across wk halves via LDS
#pragma unroll
  for (int r = 0; r < 16; r++) {
#pragma unroll
    for (int msk = 1; msk < 32; msk <<= 1)
      l_part[r] += __shfl_xor(l_part[r], msk, 64);
  }
  if (l32 == 0) {
#pragma unroll
    for (int r = 0; r < 16; r++) {
      int rowl = (r & 3) + 8 * (r >> 2) + 4 * half;
      Ls[wk][wq * 32 + rowl] = l_part[r];
    }
  }
  __syncthreads();

  const int bb = bh >> 3, h = bh & 7;
#pragma unroll
  for (int r = 0; r < 16; r++) {
    int rowl = (r & 3) + 8 * (r >> 2) + 4 * half;
    float l = Ls[0][wq * 32 + rowl] + Ls[1][wq * 32 + rowl];
    float val = o[r] * __builtin_amdgcn_rcpf(l);
    int row = q0 + wq * 32 + rowl;
    Og[((size_t)bb * 2048 + row) * 512 + h * 64 + wk * 32 + l32] = f2bf(val);
  }
}

// ---------------------------------------------------------------------------
extern "C" void kernel_launch(void* const* d_in, const int* in_sizes, int n_in,
                              void* d_out, int out_size, void* d_ws, size_t ws_size,
                              hipStream_t stream) {
  const float* x    = (const float*)d_in[0];   // [4][2048][512]
  const float* Wqkv = (const float*)d_in[1];   // [1536][512]
  const float* Wout = (const float*)d_in[2];   // [512][512]
  float* y = (float*)d_out;                    // [4][2048][512]

  char* ws = (char*)d_ws;
  size_t off = 0;
  auto alloc = [&](size_t bytes) {
    void* p = ws + off;
    off += (bytes + 255) & ~(size_t)255;
    return p;
  };
  u16* xb    = (u16*)alloc((size_t)8192 * 512 * 2);
  u16* wqkvb = (u16*)alloc((size_t)1536 * 512 * 2);
  u16* woutb = (u16*)alloc((size_t)512 * 512 * 2);
  u16* Qw    = (u16*)alloc((size_t)32 * 2048 * 64 * 2);
  u16* Kw    = (u16*)alloc((size_t)32 * 2048 * 64 * 2);
  u16* Vw    = (u16*)alloc((size_t)32 * 2048 * 64 * 2);  // transposed [bh][d][n]
  u16* Ow    = (u16*)alloc((size_t)8192 * 512 * 2);
  if (off > ws_size) return;

  cvt4<<<4096, 256, 0, stream>>>(x, xb, 8192 * 512 / 4);
  cvt4<<<768, 256, 0, stream>>>(Wqkv, wqkvb, 1536 * 512 / 4);
  cvt4<<<256, 256, 0, stream>>>(Wout, woutb, 512 * 512 / 4);

  gemm128<128, 0><<<dim3(64, 12), 256, 0, stream>>>(xb, wqkvb, nullptr, Qw, Kw, Vw);
  attn_kernel<<<dim3(32, 32), 256, 0, stream>>>(Qw, Kw, Vw, Ow);
  gemm128<64, 1><<<dim3(64, 8), 256, 0, stream>>>(Ow, woutb, y, nullptr, nullptr, nullptr);
}

// Round 4
// 175.101 us; speedup vs baseline: 1.1275x; 1.1275x over previous
//
#include <hip/hip_runtime.h>

// ---------------------------------------------------------------------------
// Attention block: y = (softmax(scale*(xWq)(xWk)^T) (xWv)) Wout^T
// b=4 n=2048 c=512 h=8 d=64.  bf16 MFMA, fp32 accumulate.
//
// R3:
//   - attn: REVERT R2's shfl-packing (__shfl_xor = ds_bpermute = LDS pipe!)
//     back to R1's plain ds_write_b16 Ps path (proven 72.6 us).
//   - gemm1 epilogue: V-part blocks transpose through LDS (swizzled) and
//     store coalesced b128 along tok, replacing the 64-line/inst u16 scatter.
//
// Fragment layouts (HW-verified, guide §3):
//   16x16x32: A[m=lane&15][k=(lane>>4)*8+j], C/D: col=lane&15, row=(lane>>4)*4+reg
//   32x32x16: A[m=lane&31][k=(lane>>5)*8+j], C/D: col=lane&31,
//             row=(reg&3)+8*(reg>>2)+4*(lane>>5)
// ---------------------------------------------------------------------------

typedef unsigned short u16;
typedef __attribute__((ext_vector_type(8))) short s16x8;
typedef __attribute__((ext_vector_type(4))) float f32x4;
typedef __attribute__((ext_vector_type(16))) float f32x16;

__device__ __forceinline__ u16 f2bf(float f) {
  unsigned int u = __float_as_uint(f);
  u = (u + 0x7fffu + ((u >> 16) & 1u)) >> 16;   // RNE
  return (u16)u;
}

// async global->LDS, 16 B per lane; lds_base must be wave-uniform
__device__ __forceinline__ void gload16(const u16* g, u16* lds_base) {
  __builtin_amdgcn_global_load_lds(
      (const __attribute__((address_space(1))) unsigned int*)g,
      (__attribute__((address_space(3))) unsigned int*)lds_base, 16, 0, 0);
}

// ---- fp32 -> bf16 bulk convert (4 elems/thread) ---------------------------
__global__ __launch_bounds__(256) void cvt4(const float* __restrict__ in,
                                            u16* __restrict__ out, int n4) {
  int i = blockIdx.x * 256 + threadIdx.x;
  if (i >= n4) return;
  float4 f = ((const float4*)in)[i];
  uint2 o;
  o.x = (unsigned)f2bf(f.x) | ((unsigned)f2bf(f.y) << 16);
  o.y = (unsigned)f2bf(f.z) | ((unsigned)f2bf(f.w) << 16);
  ((uint2*)out)[i] = o;
}

// ---- GEMM  C[M][N] = A[M][512] * B[N][512]^T  (m97-style) -----------------
// 128 x BN tile, BK=64, 4 waves (2x2), per-wave 64 x BN/2 via 16x16x32.
// LDS: row-major [rows][64] u16, 16B chunk c of row r at slot (c ^ (r&7)):
// DMA-contiguous AND ~conflict-free b128 frag reads.
// MODE 0: Q(*scale*log2e)/K scatter -> [bh][n][64]; V -> [bh][d][n] via
//         LDS transpose + coalesced b128 stores.
// MODE 1: fp32 store to Cf (ldc=512).
template <int BN, int MODE>
__global__ __launch_bounds__(256) void gemm128(
    const u16* __restrict__ A, const u16* __restrict__ B,
    float* __restrict__ Cf,
    u16* __restrict__ Qp, u16* __restrict__ Kp, u16* __restrict__ Vp) {
  constexpr int K = 512;
  constexpr int JN = BN / 32;           // n-blocks per wave
  __shared__ u16 smem[128 * 64 + BN * 64];
  u16* As = smem;
  u16* Bs = smem + 128 * 64;
  const int bm0 = blockIdx.x * 128, bn0 = blockIdx.y * BN;
  const int t = threadIdx.x, wave = t >> 6, lane = t & 63;
  const int quad = lane >> 4, l16 = lane & 15;
  const int wm = (wave & 1) * 64, wn = (wave >> 1) * (BN / 2);
  const int lr = lane >> 3, lc = lane & 7;   // staging: 8 rows x 8 chunks
  const int swz = lc ^ lr;

  f32x4 acc[4][JN] = {};

  for (int k0 = 0; k0 < K; k0 += 64) {
    __syncthreads();
#pragma unroll
    for (int a = 0; a < 4; a++) {
      int r = wave * 32 + a * 8 + lr;
      gload16(A + (size_t)(bm0 + r) * K + k0 + swz * 8,
              &As[(wave * 32 + a * 8) * 64]);
    }
#pragma unroll
    for (int b = 0; b < BN / 32; b++) {
      int r = wave * (BN / 4) + b * 8 + lr;
      gload16(B + (size_t)(bn0 + r) * K + k0 + swz * 8,
              &Bs[(wave * (BN / 4) + b * 8) * 64]);
    }
    __syncthreads();
#pragma unroll
    for (int ks = 0; ks < 2; ks++) {
      s16x8 af[4], bf[JN];
#pragma unroll
      for (int i = 0; i < 4; i++) {
        int m = wm + i * 16 + l16;
        af[i] = *(const s16x8*)(&As[m * 64 + (((ks * 4 + quad) ^ (m & 7)) * 8)]);
      }
#pragma unroll
      for (int j = 0; j < JN; j++) {
        int n = wn + j * 16 + l16;
        bf[j] = *(const s16x8*)(&Bs[n * 64 + (((ks * 4 + quad) ^ (n & 7)) * 8)]);
      }
#pragma unroll
      for (int i = 0; i < 4; i++)
#pragma unroll
        for (int j = 0; j < JN; j++)
          acc[i][j] = __builtin_amdgcn_mfma_f32_16x16x32_bf16(af[i], bf[j], acc[i][j], 0, 0, 0);
    }
  }

  if constexpr (MODE == 1) {
#pragma unroll
    for (int i = 0; i < 4; i++)
#pragma unroll
      for (int j = 0; j < JN; j++)
#pragma unroll
        for (int r = 0; r < 4; r++) {
          int m = bm0 + wm + i * 16 + quad * 4 + r;
          int n = bn0 + wn + j * 16 + l16;
          Cf[(size_t)m * 512 + n] = acc[i][j][r];
        }
  } else {
    const int part = bn0 >> 9;   // uniform per block (BN=128 divides 512)
    if (part < 2) {
      // Q/K: dh-contiguous scatter (4 lines/inst) is acceptable
#pragma unroll
      for (int i = 0; i < 4; i++)
#pragma unroll
        for (int j = 0; j < JN; j++)
#pragma unroll
          for (int r = 0; r < 4; r++) {
            int m = bm0 + wm + i * 16 + quad * 4 + r;
            int n = bn0 + wn + j * 16 + l16;
            int oin = n & 511;
            int head = oin >> 6, dh = oin & 63;
            int bb = m >> 11, tok = m & 2047;
            size_t idx = ((size_t)(bb * 8 + head) * 2048 + tok) * 64 + dh;
            if (part == 0)
              Qp[idx] = f2bf(acc[i][j][r] * 0.18033688011112042f);  // scale*log2e
            else
              Kp[idx] = f2bf(acc[i][j][r]);
          }
    } else {
      // V: transpose via LDS (reuse smem), coalesced b128 stores along tok.
      __syncthreads();   // all frag reads of smem done
#pragma unroll
      for (int i = 0; i < 4; i++)
#pragma unroll
        for (int j = 0; j < JN; j++)
#pragma unroll
          for (int r = 0; r < 4; r++) {
            int row = wm + i * 16 + quad * 4 + r;          // tok within tile
            int cn = wn + j * 16 + l16;                    // n within tile
            smem[row * 128 + (cn ^ (row & 7))] = f2bf(acc[i][j][r]);
          }
      __syncthreads();
      const int bb = bm0 >> 11;
      const int tokbase = bm0 & 2047;
      const int headbase = (bn0 & 511) >> 6;
#pragma unroll
      for (int it = 0; it < 8; it++) {
        int cn = it * 16 + (t >> 4);
        int dh = cn & 63, head = headbase + (cn >> 6);
        int tok0 = (t & 15) * 8;
        s16x8 pk;
#pragma unroll
        for (int k = 0; k < 8; k++) {
          int row = tok0 + k;
          pk[k] = (short)smem[row * 128 + (cn ^ (row & 7))];
        }
        *(s16x8*)(&Vp[((size_t)(bb * 8 + head) * 64 + dh) * 2048 + tokbase + tok0]) = pk;
      }
    }
  }
}

// ---- attention: one block = one (b,h) x 64 Q rows, 32x32x16 MFMA ----------
// Q/K: [32][2048][64] bf16; Vt: [32][64][2048] bf16; O: [4][2048][512] bf16.
__global__ __launch_bounds__(256) void attn_kernel(
    const u16* __restrict__ Qg, const u16* __restrict__ Kg,
    const u16* __restrict__ Vtg, u16* __restrict__ Og) {
  __shared__ u16 Qs[64][72];
  __shared__ u16 Ks[64][72];
  __shared__ u16 Vt[64][72];   // Vt[d][j]
  __shared__ u16 Ps[64][72];   // P round-trip C-layout -> A-layout
  __shared__ float Ls[2][64];  // per-wk-half row sums
  const int bh = blockIdx.y;          // 0..31
  const int q0 = blockIdx.x * 64;
  const u16* Qh = Qg + (size_t)bh * 2048 * 64;
  const u16* Kh = Kg + (size_t)bh * 2048 * 64;
  const u16* Vh = Vtg + (size_t)bh * 64 * 2048;
  const int t = threadIdx.x, lane = t & 63, wave = t >> 6;
  const int wq = wave & 1, wk = wave >> 1;   // 2x2 wave grid
  const int l32 = lane & 31, half = lane >> 5;
  const int srow = t >> 2, scolb = (t & 3) * 8;

  // stage Q tile (resident) then hoist A-fragments to registers
#pragma unroll
  for (int p = 0; p < 2; p++) {
    int col = scolb + p * 32;
    *(s16x8*)(&Qs[srow][col]) = *(const s16x8*)(Qh + (size_t)(q0 + srow) * 64 + col);
  }
  __syncthreads();
  s16x8 aq[4];
#pragma unroll
  for (int ks = 0; ks < 4; ks++)
    aq[ks] = *(const s16x8*)(&Qs[wq * 32 + l32][ks * 16 + half * 8]);

  f32x16 o = {};
  float l_part[16];
#pragma unroll
  for (int r = 0; r < 16; r++) l_part[r] = 0.f;

  for (int j0 = 0; j0 < 2048; j0 += 64) {
    __syncthreads();   // prior tile's frag reads done before overwrite
#pragma unroll
    for (int p = 0; p < 2; p++) {
      int col = scolb + p * 32;
      *(s16x8*)(&Ks[srow][col]) = *(const s16x8*)(Kh + (size_t)(j0 + srow) * 64 + col);
      *(s16x8*)(&Vt[srow][col]) = *(const s16x8*)(Vh + (size_t)srow * 2048 + j0 + col);
    }
    __syncthreads();

    // S block: rows wq*32..+31, cols wk*32..+31, contraction over 64
    f32x16 s = {};
#pragma unroll
    for (int ks = 0; ks < 4; ks++) {
      s16x8 bk = *(const s16x8*)(&Ks[wk * 32 + l32][ks * 16 + half * 8]);
      s = __builtin_amdgcn_mfma_f32_32x32x16_bf16(aq[ks], bk, s, 0, 0, 0);
    }

    // p = 2^s (log2e pre-folded); l from truncated-bf16 p (plain b16 writes —
    // NO shuffles: __shfl_* is ds_bpermute = LDS pipe on CDNA)
#pragma unroll
    for (int r = 0; r < 16; r++) {
      float p = __builtin_amdgcn_exp2f(s[r]);
      unsigned u = __float_as_uint(p);
      l_part[r] += __uint_as_float(u & 0xffff0000u);
      int row = (r & 3) + 8 * (r >> 2) + 4 * half + wq * 32;
      Ps[row][wk * 32 + l32] = (u16)(u >> 16);
    }
    __syncthreads();   // Ps rows mix wk halves -> cross-wave

    // O block: rows wq*32..+31, d-cols wk*32..+31, contraction over 64 j
#pragma unroll
    for (int ks = 0; ks < 4; ks++) {
      s16x8 ap = *(const s16x8*)(&Ps[wq * 32 + l32][ks * 16 + half * 8]);
      s16x8 bv = *(const s16x8*)(&Vt[wk * 32 + l32][ks * 16 + half * 8]);
      o = __builtin_amdgcn_mfma_f32_32x32x16_bf16(ap, bv, o, 0, 0, 0);
    }
  }

  // row-sum reduce: over 32 cols in-wave, then across wk halves via LDS
#pragma unroll
  for (int r = 0; r < 16; r++) {
#pragma unroll
    for (int msk = 1; msk < 32; msk <<= 1)
      l_part[r] += __shfl_xor(l_part[r], msk, 64);
  }
  if (l32 == 0) {
#pragma unroll
    for (int r = 0; r < 16; r++) {
      int rowl = (r & 3) + 8 * (r >> 2) + 4 * half;
      Ls[wk][wq * 32 + rowl] = l_part[r];
    }
  }
  __syncthreads();

  const int bb = bh >> 3, h = bh & 7;
#pragma unroll
  for (int r = 0; r < 16; r++) {
    int rowl = (r & 3) + 8 * (r >> 2) + 4 * half;
    float l = Ls[0][wq * 32 + rowl] + Ls[1][wq * 32 + rowl];
    float val = o[r] * __builtin_amdgcn_rcpf(l);
    int row = q0 + wq * 32 + rowl;
    Og[((size_t)bb * 2048 + row) * 512 + h * 64 + wk * 32 + l32] = f2bf(val);
  }
}

// ---------------------------------------------------------------------------
extern "C" void kernel_launch(void* const* d_in, const int* in_sizes, int n_in,
                              void* d_out, int out_size, void* d_ws, size_t ws_size,
                              hipStream_t stream) {
  const float* x    = (const float*)d_in[0];   // [4][2048][512]
  const float* Wqkv = (const float*)d_in[1];   // [1536][512]
  const float* Wout = (const float*)d_in[2];   // [512][512]
  float* y = (float*)d_out;                    // [4][2048][512]

  char* ws = (char*)d_ws;
  size_t off = 0;
  auto alloc = [&](size_t bytes) {
    void* p = ws + off;
    off += (bytes + 255) & ~(size_t)255;
    return p;
  };
  u16* xb    = (u16*)alloc((size_t)8192 * 512 * 2);
  u16* wqkvb = (u16*)alloc((size_t)1536 * 512 * 2);
  u16* woutb = (u16*)alloc((size_t)512 * 512 * 2);
  u16* Qw    = (u16*)alloc((size_t)32 * 2048 * 64 * 2);
  u16* Kw    = (u16*)alloc((size_t)32 * 2048 * 64 * 2);
  u16* Vw    = (u16*)alloc((size_t)32 * 2048 * 64 * 2);  // transposed [bh][d][n]
  u16* Ow    = (u16*)alloc((size_t)8192 * 512 * 2);
  if (off > ws_size) return;

  cvt4<<<4096, 256, 0, stream>>>(x, xb, 8192 * 512 / 4);
  cvt4<<<768, 256, 0, stream>>>(Wqkv, wqkvb, 1536 * 512 / 4);
  cvt4<<<256, 256, 0, stream>>>(Wout, woutb, 512 * 512 / 4);

  gemm128<128, 0><<<dim3(64, 12), 256, 0, stream>>>(xb, wqkvb, nullptr, Qw, Kw, Vw);
  attn_kernel<<<dim3(32, 32), 256, 0, stream>>>(Qw, Kw, Vw, Ow);
  gemm128<64, 1><<<dim3(64, 8), 256, 0, stream>>>(Ow, woutb, y, nullptr, nullptr, nullptr);
}

// Round 5
// 171.216 us; speedup vs baseline: 1.1531x; 1.0227x over previous
//
#include <hip/hip_runtime.h>

// ---------------------------------------------------------------------------
// Attention block: y = (softmax(scale*(xWq)(xWk)^T) (xWv)) Wout^T
// b=4 n=2048 c=512 h=8 d=64.  bf16 MFMA, fp32 accumulate.
//
// R4:
//   - attn computes S^T (A=K, B=Q) so P exits the MFMA with q-on-lanes /
//     kv-in-regs = the PV B-operand layout.  v_perm_b32 pair-packing +
//     v_permlane32_swap_b32 (gfx950 VALU cross-lane) rebuild PV B-frags
//     IN REGISTERS: no Ps LDS round-trip, no per-tile 3rd barrier, l is
//     pure in-lane adds.  O^T merged/normalized once per block via LDS.
//   - 3 cvt launches fused into 1.
//   - GEMMs unchanged from R3 (isolate attribution; they'll surface in
//     the top-5 now that attn shrinks).
//
// Fragment layouts (HW-verified, guide §3):
//   32x32x16: A/B [idx=lane&31][k=(lane>>5)*8+j], C/D: col=lane&31,
//             row=(reg&3)+8*(reg>>2)+4*(lane>>5)
// ---------------------------------------------------------------------------

typedef unsigned short u16;
typedef __attribute__((ext_vector_type(8))) short s16x8;
typedef __attribute__((ext_vector_type(4))) float f32x4;
typedef __attribute__((ext_vector_type(16))) float f32x16;

__device__ __forceinline__ u16 f2bf(float f) {
  unsigned int u = __float_as_uint(f);
  u = (u + 0x7fffu + ((u >> 16) & 1u)) >> 16;   // RNE
  return (u16)u;
}

// async global->LDS, 16 B per lane; lds_base must be wave-uniform
__device__ __forceinline__ void gload16(const u16* g, u16* lds_base) {
  __builtin_amdgcn_global_load_lds(
      (const __attribute__((address_space(1))) unsigned int*)g,
      (__attribute__((address_space(3))) unsigned int*)lds_base, 16, 0, 0);
}

// swap low/high 32-lane halves between two VGPRs (VALU pipe, gfx950)
__device__ __forceinline__ void permlane32_swap(unsigned& a, unsigned& b) {
  asm volatile("v_permlane32_swap_b32 %0, %1" : "+v"(a), "+v"(b));
}

// ---- fused fp32 -> bf16 convert for x, W_qkv, W_out -----------------------
__global__ __launch_bounds__(256) void cvt_all(
    const float* __restrict__ x, const float* __restrict__ w1,
    const float* __restrict__ w2, u16* __restrict__ xb,
    u16* __restrict__ w1b, u16* __restrict__ w2b) {
  constexpr int N1 = 8192 * 512 / 4, N2 = 1536 * 512 / 4, N3 = 512 * 512 / 4;
  int i = blockIdx.x * 256 + threadIdx.x;
  if (i >= N1 + N2 + N3) return;
  const float* src;
  u16* dst;
  int j;
  if (i < N1) { src = x; dst = xb; j = i; }
  else if (i < N1 + N2) { src = w1; dst = w1b; j = i - N1; }
  else { src = w2; dst = w2b; j = i - N1 - N2; }
  float4 f = ((const float4*)src)[j];
  uint2 o;
  o.x = (unsigned)f2bf(f.x) | ((unsigned)f2bf(f.y) << 16);
  o.y = (unsigned)f2bf(f.z) | ((unsigned)f2bf(f.w) << 16);
  ((uint2*)dst)[j] = o;
}

// ---- GEMM  C[M][N] = A[M][512] * B[N][512]^T  (m97-style, unchanged R3) ---
template <int BN, int MODE>
__global__ __launch_bounds__(256) void gemm128(
    const u16* __restrict__ A, const u16* __restrict__ B,
    float* __restrict__ Cf,
    u16* __restrict__ Qp, u16* __restrict__ Kp, u16* __restrict__ Vp) {
  constexpr int K = 512;
  constexpr int JN = BN / 32;
  __shared__ u16 smem[128 * 64 + BN * 64];
  u16* As = smem;
  u16* Bs = smem + 128 * 64;
  const int bm0 = blockIdx.x * 128, bn0 = blockIdx.y * BN;
  const int t = threadIdx.x, wave = t >> 6, lane = t & 63;
  const int quad = lane >> 4, l16 = lane & 15;
  const int wm = (wave & 1) * 64, wn = (wave >> 1) * (BN / 2);
  const int lr = lane >> 3, lc = lane & 7;
  const int swz = lc ^ lr;

  f32x4 acc[4][JN] = {};

  for (int k0 = 0; k0 < K; k0 += 64) {
    __syncthreads();
#pragma unroll
    for (int a = 0; a < 4; a++) {
      int r = wave * 32 + a * 8 + lr;
      gload16(A + (size_t)(bm0 + r) * K + k0 + swz * 8,
              &As[(wave * 32 + a * 8) * 64]);
    }
#pragma unroll
    for (int b = 0; b < BN / 32; b++) {
      int r = wave * (BN / 4) + b * 8 + lr;
      gload16(B + (size_t)(bn0 + r) * K + k0 + swz * 8,
              &Bs[(wave * (BN / 4) + b * 8) * 64]);
    }
    __syncthreads();
#pragma unroll
    for (int ks = 0; ks < 2; ks++) {
      s16x8 af[4], bf[JN];
#pragma unroll
      for (int i = 0; i < 4; i++) {
        int m = wm + i * 16 + l16;
        af[i] = *(const s16x8*)(&As[m * 64 + (((ks * 4 + quad) ^ (m & 7)) * 8)]);
      }
#pragma unroll
      for (int j = 0; j < JN; j++) {
        int n = wn + j * 16 + l16;
        bf[j] = *(const s16x8*)(&Bs[n * 64 + (((ks * 4 + quad) ^ (n & 7)) * 8)]);
      }
#pragma unroll
      for (int i = 0; i < 4; i++)
#pragma unroll
        for (int j = 0; j < JN; j++)
          acc[i][j] = __builtin_amdgcn_mfma_f32_16x16x32_bf16(af[i], bf[j], acc[i][j], 0, 0, 0);
    }
  }

  if constexpr (MODE == 1) {
#pragma unroll
    for (int i = 0; i < 4; i++)
#pragma unroll
      for (int j = 0; j < JN; j++)
#pragma unroll
        for (int r = 0; r < 4; r++) {
          int m = bm0 + wm + i * 16 + quad * 4 + r;
          int n = bn0 + wn + j * 16 + l16;
          Cf[(size_t)m * 512 + n] = acc[i][j][r];
        }
  } else {
    const int part = bn0 >> 9;
    if (part < 2) {
#pragma unroll
      for (int i = 0; i < 4; i++)
#pragma unroll
        for (int j = 0; j < JN; j++)
#pragma unroll
          for (int r = 0; r < 4; r++) {
            int m = bm0 + wm + i * 16 + quad * 4 + r;
            int n = bn0 + wn + j * 16 + l16;
            int oin = n & 511;
            int head = oin >> 6, dh = oin & 63;
            int bb = m >> 11, tok = m & 2047;
            size_t idx = ((size_t)(bb * 8 + head) * 2048 + tok) * 64 + dh;
            if (part == 0)
              Qp[idx] = f2bf(acc[i][j][r] * 0.18033688011112042f);  // scale*log2e
            else
              Kp[idx] = f2bf(acc[i][j][r]);
          }
    } else {
      // V: transpose via LDS (reuse smem), coalesced b128 stores along tok.
      __syncthreads();
#pragma unroll
      for (int i = 0; i < 4; i++)
#pragma unroll
        for (int j = 0; j < JN; j++)
#pragma unroll
          for (int r = 0; r < 4; r++) {
            int row = wm + i * 16 + quad * 4 + r;
            int cn = wn + j * 16 + l16;
            smem[row * 128 + (cn ^ (row & 7))] = f2bf(acc[i][j][r]);
          }
      __syncthreads();
      const int bb = bm0 >> 11;
      const int tokbase = bm0 & 2047;
      const int headbase = (bn0 & 511) >> 6;
#pragma unroll
      for (int it = 0; it < 8; it++) {
        int cn = it * 16 + (t >> 4);
        int dh = cn & 63, head = headbase + (cn >> 6);
        int tok0 = (t & 15) * 8;
        s16x8 pk;
#pragma unroll
        for (int k = 0; k < 8; k++) {
          int row = tok0 + k;
          pk[k] = (short)smem[row * 128 + (cn ^ (row & 7))];
        }
        *(s16x8*)(&Vp[((size_t)(bb * 8 + head) * 64 + dh) * 2048 + tokbase + tok0]) = pk;
      }
    }
  }
}

// ---- attention: one block = one (b,h) x 64 Q rows, 32x32x16 MFMA ----------
// Computes S^T = K.Q^T so P lands in the PV B-operand layout; PV B-frags
// built in registers via v_perm pack + v_permlane32_swap.  No Ps LDS.
// Q/K: [32][2048][64] bf16; Vt: [32][64][2048] bf16; O: [4][2048][512] bf16.
__global__ __launch_bounds__(256) void attn_kernel(
    const u16* __restrict__ Qg, const u16* __restrict__ Kg,
    const u16* __restrict__ Vtg, u16* __restrict__ Og) {
  __shared__ __attribute__((aligned(16))) u16 smem[3 * 64 * 72];  // 27648 B
  u16* Qs = smem;              // [64][72]
  u16* Ks = smem + 64 * 72;    // [64][72]
  u16* Vt = smem + 2 * 64 * 72;  // [64][72]  Vt[d][j_local]
  float* Obuf = (float*)smem;                     // phase2: [64][68] fp32
  float* Lbuf = (float*)((char*)smem + 64 * 68 * 4);  // [4][64] fp32

  const int bh = blockIdx.y;
  const int q0 = blockIdx.x * 64;
  const u16* Qh = Qg + (size_t)bh * 2048 * 64;
  const u16* Kh = Kg + (size_t)bh * 2048 * 64;
  const u16* Vh = Vtg + (size_t)bh * 64 * 2048;
  const int t = threadIdx.x, lane = t & 63, wave = t >> 6;
  const int wq = wave & 1, wk = wave >> 1;   // wq: q-half, wk: kv-half
  const int l32 = lane & 31, half = lane >> 5;
  const int srow = t >> 2, scolb = (t & 3) * 8;
  const int q = wq * 32 + l32;               // this lane's q row (local)

  // stage Q tile, hoist B-operand fragments (resident all 32 KV tiles)
#pragma unroll
  for (int p = 0; p < 2; p++) {
    int col = scolb + p * 32;
    *(s16x8*)(&Qs[srow * 72 + col]) = *(const s16x8*)(Qh + (size_t)(q0 + srow) * 64 + col);
  }
  __syncthreads();
  s16x8 bQ[4];
#pragma unroll
  for (int ks = 0; ks < 4; ks++)
    bQ[ks] = *(const s16x8*)(&Qs[q * 72 + ks * 16 + half * 8]);

  f32x16 o[2] = {};   // O^T partial: rows d (regs), cols q (lanes), kv-half wk
  float l_acc = 0.f;

  for (int j0 = 0; j0 < 2048; j0 += 64) {
    __syncthreads();
#pragma unroll
    for (int p = 0; p < 2; p++) {
      int col = scolb + p * 32;
      *(s16x8*)(&Ks[srow * 72 + col]) = *(const s16x8*)(Kh + (size_t)(j0 + srow) * 64 + col);
      *(s16x8*)(&Vt[srow * 72 + col]) = *(const s16x8*)(Vh + (size_t)srow * 2048 + j0 + col);
    }
    __syncthreads();

    // S^T block: rows kv = wk*32..+31 (regs), cols q = wq*32+l32 (lanes)
    f32x16 s = {};
#pragma unroll
    for (int ks = 0; ks < 4; ks++) {
      s16x8 aK = *(const s16x8*)(&Ks[(wk * 32 + l32) * 72 + ks * 16 + half * 8]);
      s = __builtin_amdgcn_mfma_f32_32x32x16_bf16(aK, bQ[ks], s, 0, 0, 0);
    }

    // p = 2^s; l accumulates in-lane (q is lane-resident now);
    // pack row-pairs to bf16x2 (v_perm truncation) and half-swap into
    // PV B-fragments -- all VALU, zero LDS
    unsigned pu[16];
#pragma unroll
    for (int r = 0; r < 16; r++) {
      float p = __builtin_amdgcn_exp2f(s[r]);
      unsigned u = __float_as_uint(p);
      l_acc += __uint_as_float(u & 0xffff0000u);
      pu[r] = u;
    }
    unsigned g[8];
#pragma unroll
    for (int v = 0; v < 8; v++)
      g[v] = __builtin_amdgcn_perm(pu[2 * v + 1], pu[2 * v], 0x07060302u);
    permlane32_swap(g[0], g[2]);
    permlane32_swap(g[1], g[3]);
    permlane32_swap(g[4], g[6]);
    permlane32_swap(g[5], g[7]);
    s16x8 bP[2];
    ((unsigned*)&bP[0])[0] = g[0]; ((unsigned*)&bP[0])[1] = g[1];
    ((unsigned*)&bP[0])[2] = g[2]; ((unsigned*)&bP[0])[3] = g[3];
    ((unsigned*)&bP[1])[0] = g[4]; ((unsigned*)&bP[1])[1] = g[5];
    ((unsigned*)&bP[1])[2] = g[6]; ((unsigned*)&bP[1])[3] = g[7];

    // O^T += V^T . P^T over this wave's kv half (A=Vt rows d, B=P^T)
#pragma unroll
    for (int dt = 0; dt < 2; dt++)
#pragma unroll
      for (int s2 = 0; s2 < 2; s2++) {
        s16x8 aV = *(const s16x8*)(&Vt[(dt * 32 + l32) * 72 + wk * 32 + s2 * 16 + half * 8]);
        o[dt] = __builtin_amdgcn_mfma_f32_32x32x16_bf16(aV, bP[s2], o[dt], 0, 0, 0);
      }
  }

  // ---- merge kv-halves (wk pairs), normalize, coalesced store ----
  __syncthreads();   // last tile's Vt/Ks reads done; smem now reused as Obuf
  Lbuf[(wk * 2 + half) * 64 + q] = l_acc;
  if (wk == 1) {
#pragma unroll
    for (int dt = 0; dt < 2; dt++)
#pragma unroll
      for (int gi = 0; gi < 4; gi++) {
        int d0 = 8 * gi + 4 * half + 32 * dt;
        float4 v = { o[dt][4 * gi + 0], o[dt][4 * gi + 1],
                     o[dt][4 * gi + 2], o[dt][4 * gi + 3] };
        *(float4*)(&Obuf[q * 68 + d0]) = v;
      }
  }
  __syncthreads();
  if (wk == 0) {
    float l = Lbuf[0 * 64 + q] + Lbuf[1 * 64 + q] + Lbuf[2 * 64 + q] + Lbuf[3 * 64 + q];
    float sc = __builtin_amdgcn_rcpf(l);
#pragma unroll
    for (int dt = 0; dt < 2; dt++)
#pragma unroll
      for (int gi = 0; gi < 4; gi++) {
        int d0 = 8 * gi + 4 * half + 32 * dt;
        float4 v = *(float4*)(&Obuf[q * 68 + d0]);
        v.x = (v.x + o[dt][4 * gi + 0]) * sc;
        v.y = (v.y + o[dt][4 * gi + 1]) * sc;
        v.z = (v.z + o[dt][4 * gi + 2]) * sc;
        v.w = (v.w + o[dt][4 * gi + 3]) * sc;
        *(float4*)(&Obuf[q * 68 + d0]) = v;
      }
  }
  __syncthreads();

  // coalesced store: thread t -> (q = t>>2, d0 = (t&3)*16), 32 B per thread
  {
    const int bb = bh >> 3, h = bh & 7;
    int qq = t >> 2, d0 = (t & 3) * 16;
    float f[16];
#pragma unroll
    for (int c = 0; c < 4; c++) {
      float4 v = *(float4*)(&Obuf[qq * 68 + d0 + 4 * c]);
      f[4 * c + 0] = v.x; f[4 * c + 1] = v.y; f[4 * c + 2] = v.z; f[4 * c + 3] = v.w;
    }
    unsigned pk[8];
#pragma unroll
    for (int c = 0; c < 8; c++)
      pk[c] = (unsigned)f2bf(f[2 * c]) | ((unsigned)f2bf(f[2 * c + 1]) << 16);
    size_t base = ((size_t)bb * 2048 + q0 + qq) * 512 + h * 64 + d0;
    uint4 s0 = { pk[0], pk[1], pk[2], pk[3] };
    uint4 s1 = { pk[4], pk[5], pk[6], pk[7] };
    *(uint4*)(&Og[base]) = s0;
    *(uint4*)(&Og[base + 8]) = s1;
  }
}

// ---------------------------------------------------------------------------
extern "C" void kernel_launch(void* const* d_in, const int* in_sizes, int n_in,
                              void* d_out, int out_size, void* d_ws, size_t ws_size,
                              hipStream_t stream) {
  const float* x    = (const float*)d_in[0];   // [4][2048][512]
  const float* Wqkv = (const float*)d_in[1];   // [1536][512]
  const float* Wout = (const float*)d_in[2];   // [512][512]
  float* y = (float*)d_out;                    // [4][2048][512]

  char* ws = (char*)d_ws;
  size_t off = 0;
  auto alloc = [&](size_t bytes) {
    void* p = ws + off;
    off += (bytes + 255) & ~(size_t)255;
    return p;
  };
  u16* xb    = (u16*)alloc((size_t)8192 * 512 * 2);
  u16* wqkvb = (u16*)alloc((size_t)1536 * 512 * 2);
  u16* woutb = (u16*)alloc((size_t)512 * 512 * 2);
  u16* Qw    = (u16*)alloc((size_t)32 * 2048 * 64 * 2);
  u16* Kw    = (u16*)alloc((size_t)32 * 2048 * 64 * 2);
  u16* Vw    = (u16*)alloc((size_t)32 * 2048 * 64 * 2);  // transposed [bh][d][n]
  u16* Ow    = (u16*)alloc((size_t)8192 * 512 * 2);
  if (off > ws_size) return;

  cvt_all<<<5120, 256, 0, stream>>>(x, Wqkv, Wout, xb, wqkvb, woutb);

  gemm128<128, 0><<<dim3(64, 12), 256, 0, stream>>>(xb, wqkvb, nullptr, Qw, Kw, Vw);
  attn_kernel<<<dim3(32, 32), 256, 0, stream>>>(Qw, Kw, Vw, Ow);
  gemm128<64, 1><<<dim3(64, 8), 256, 0, stream>>>(Ow, woutb, y, nullptr, nullptr, nullptr);
}